// Round 7
// baseline (444.459 us; speedup 1.0000x reference)
//
#include <hip/hip_runtime.h>
#include <cstdint>

// ===================== GCN encoder on MI355X =====================
// out = gcn(relu(gcn(x, W1, b1)), W2, b2)
// gcn(x,W,b)[i] = dinv[i] * ( sum_{e: dst=i} (xW*dinv)[src] + (xW*dinv)[i] ) + b
// dinv = rsqrt(indeg+1) (self-loop), identical for both layers.
//
// R13 = R12 with the REAL R11/R12 bug fixed: the fused-epilogue A-fragment
// shfls were inside `am ? __shfl(..) : 0` -> divergent exec; shfl source
// lanes (8-11, 24-27, ...) were INACTIVE -> ds_bpermute from inactive
// lanes is undefined -> deterministic garbage (identical absmax 0.1965 in
// both R11 and R12). Fix: issue all shfls unconditionally (full exec,
// convergent intrinsic), select afterwards.
// Carried content:
//  (a) agg1 fused gemm2 per-wave (no post-gather barrier; waves retire
//      independently -- R10's +11us was block-barrier degree-tail coupling).
//  (b) gemm1 co-dispatched with bscatter; deg via global atomics in hist,
//      dinv in scancol, bcsr reads deg_g.
//  (c) bscatter super-blocks CHC=32768.
//  (d) histmat aliases csr region; packed aliases bufB.

#define BSHIFT 7          // 128 nodes per bucket
#define NBMAX 784         // >= ceil(100000/128) = 782
#define CHH 8192          // edges per hist chunk
#define CHC 32768         // edges per bscatter super-block (4 chunks)
#define MAXB 6016         // LDS-cached bucket capacity (avg 4092, +30 sigma)

typedef __attribute__((ext_vector_type(8))) short bf16x8;
typedef __attribute__((ext_vector_type(4))) float f32x4;

union U8 { unsigned u[4]; bf16x8 v; };

// ---------------- bf16 helpers ----------------
__device__ inline unsigned short f2bf(float f) {
    unsigned u = __float_as_uint(f);
    unsigned r = (u + 0x7FFFu + ((u >> 16) & 1u)) >> 16;  // RNE
    return (unsigned short)r;
}
__device__ inline unsigned pack2(float a, float b) {
    return (unsigned)f2bf(a) | ((unsigned)f2bf(b) << 16);
}
__device__ inline float blo(unsigned u) { return __uint_as_float(u << 16); }
__device__ inline float bhi(unsigned u) { return __uint_as_float(u & 0xFFFF0000u); }

// ---- pass A: bucket histogram + global deg atomics + weight prep ----------
__global__ __launch_bounds__(256) void hist_kernel(const int* __restrict__ dst,
                                                   int* __restrict__ histmat,
                                                   int E, int nb, int nblk,
                                                   const float* __restrict__ W1,
                                                   const float* __restrict__ W2,
                                                   unsigned short* __restrict__ W1t,
                                                   unsigned short* __restrict__ W2t,
                                                   int* __restrict__ deg_g) {
    if (blockIdx.x >= (unsigned)nblk) {
        // weight-prep blocks: W[K][64] fp32 -> Wt[64][K] bf16
        int i = (blockIdx.x - nblk) * 256 + threadIdx.x;
        if (i < 128 * 64) {
            int k = i >> 6, n = i & 63;
            W1t[n * 128 + k] = f2bf(W1[i]);
        }
        int j = i - 128 * 64;
        if (j >= 0 && j < 64 * 64) {
            int k = j >> 6, n = j & 63;
            W2t[n * 64 + k] = f2bf(W2[j]);
        }
        return;
    }
    __shared__ int hist[NBMAX];
    int t = threadIdx.x;
    for (int b = t; b < nb; b += 256) hist[b] = 0;
    __syncthreads();
    int base = blockIdx.x * CHH;
#pragma unroll
    for (int j = 0; j < CHH / 1024; ++j) {
        int idx = base + j * 1024 + t * 4;
        if (idx + 4 <= E) {
            int4 d = *(const int4*)(dst + idx);
            atomicAdd(&hist[d.x >> BSHIFT], 1);
            atomicAdd(&hist[d.y >> BSHIFT], 1);
            atomicAdd(&hist[d.z >> BSHIFT], 1);
            atomicAdd(&hist[d.w >> BSHIFT], 1);
            atomicAdd(&deg_g[d.x], 1);
            atomicAdd(&deg_g[d.y], 1);
            atomicAdd(&deg_g[d.z], 1);
            atomicAdd(&deg_g[d.w], 1);
        } else {
            for (int k = 0; k < 4; ++k)
                if (idx + k < E) {
                    int dd = dst[idx + k];
                    atomicAdd(&hist[dd >> BSHIFT], 1);
                    atomicAdd(&deg_g[dd], 1);
                }
        }
    }
    __syncthreads();
    for (int b = t; b < nb; b += 256) histmat[blockIdx.x * nb + b] = hist[b];
}

// ---- pass B: per-bucket scan over chunks + dinv from deg ------------------
__global__ __launch_bounds__(256) void scancol_kernel(const int* __restrict__ histmat,
                                                      int* __restrict__ colbase,
                                                      int* __restrict__ buckettotal,
                                                      int nb, int nblk,
                                                      const int* __restrict__ deg_g,
                                                      float* __restrict__ dinv, int N) {
    __shared__ int ts[256];
    int b = blockIdx.x;
    int t = threadIdx.x;
    if (t < 128) {
        int node = b * 128 + t;
        if (node < N) dinv[node] = rsqrtf((float)(deg_g[node] + 1));
    }
    int v[4];
    int tsum = 0;
#pragma unroll
    for (int k = 0; k < 4; ++k) {
        int blk = t * 4 + k;
        v[k] = (blk < nblk) ? histmat[blk * nb + b] : 0;
        tsum += v[k];
    }
    ts[t] = tsum;
    __syncthreads();
    for (int ofs = 1; ofs < 256; ofs <<= 1) {
        int val = (t >= ofs) ? ts[t - ofs] : 0;
        __syncthreads();
        ts[t] += val;
        __syncthreads();
    }
    int run = ts[t] - tsum;
#pragma unroll
    for (int k = 0; k < 4; ++k) {
        int blk = t * 4 + k;
        if (blk < nblk) colbase[blk * nb + b] = run;
        run += v[k];
    }
    if (t == 255) buckettotal[b] = ts[255];
}

// ---- gemm1 body: bufA[M,64]bf16 = (X[M,128]f32 @ W1[128,64]) * dinv -------
__device__ void gemm1_body(char* smem, const float* __restrict__ X,
                           const unsigned short* __restrict__ Wt,
                           const float* __restrict__ dinv,
                           unsigned short* __restrict__ Ybf, int M, int blk) {
    constexpr int K = 128, KP = 136;
    unsigned short* Xs = (unsigned short*)smem;       // 64*136*2 = 17408 B
    unsigned short* Ws = Xs + 64 * KP;                // 17408 B
    int t = threadIdx.x;
    int row0 = blk * 64;

    for (int i = t; i < 64 * K / 8; i += 256) {
        int r = i / (K / 8), c8 = i % (K / 8);
        *(uint4*)(&Ws[r * KP + c8 * 8]) = ((const uint4*)Wt)[i];
    }
    for (int i = t; i < 64 * K / 4; i += 256) {
        int r = i / (K / 4), c4 = i % (K / 4);
        int gr = row0 + r;
        float4 v = make_float4(0.f, 0.f, 0.f, 0.f);
        if (gr < M) v = ((const float4*)(X + (size_t)gr * K))[c4];
        uint2 p;
        p.x = pack2(v.x, v.y);
        p.y = pack2(v.z, v.w);
        *(uint2*)(&Xs[r * KP + c4 * 4]) = p;
    }
    __syncthreads();

    int lane = t & 63;
    int w = t >> 6;
    int m = lane & 15;
    int q = lane >> 4;

    f32x4 acc[4];
#pragma unroll
    for (int nt = 0; nt < 4; ++nt) acc[nt] = (f32x4){0.f, 0.f, 0.f, 0.f};

#pragma unroll
    for (int s = 0; s < K / 32; ++s) {
        bf16x8 a = *(const bf16x8*)(&Xs[(16 * w + m) * KP + s * 32 + q * 8]);
#pragma unroll
        for (int nt = 0; nt < 4; ++nt) {
            bf16x8 b = *(const bf16x8*)(&Ws[(16 * nt + m) * KP + s * 32 + q * 8]);
            acc[nt] = __builtin_amdgcn_mfma_f32_16x16x32_bf16(a, b, acc[nt], 0, 0, 0);
        }
    }
    __syncthreads();

    unsigned short* Cs = Xs;
#pragma unroll
    for (int nt = 0; nt < 4; ++nt)
#pragma unroll
        for (int r = 0; r < 4; ++r) {
            int row = 16 * w + q * 4 + r;
            int gr = row0 + row;
            float d = (gr < M) ? dinv[gr] : 0.f;
            Cs[row * 72 + nt * 16 + m] = f2bf(acc[nt][r] * d);
        }
    __syncthreads();
    for (int i = t; i < 64 * 64 / 8; i += 256) {
        int r = i >> 3, c8 = i & 7;
        int gr = row0 + r;
        if (gr < M)
            *(uint4*)(Ybf + (size_t)gr * 64 + c8 * 8) = *(const uint4*)(&Cs[r * 72 + c8 * 8]);
    }
}

// ---- pass C: scatter super-blocks + co-dispatched gemm1 -------------------
__global__ __launch_bounds__(256) void bscatter_gemm1_kernel(
        const int* __restrict__ src, const int* __restrict__ dst,
        const int* __restrict__ colbase, const int* __restrict__ buckettotal,
        int* __restrict__ packed, int E, int nb, int nblkc,
        const float* __restrict__ x, const unsigned short* __restrict__ W1t,
        const float* __restrict__ dinv, unsigned short* __restrict__ bufA, int N) {
    __shared__ char smem[2 * 64 * 136 * 2];  // 34816 B (gemm1); bscatter aliases
    int t = threadIdx.x;
    if ((int)blockIdx.x >= nblkc) {
        gemm1_body(smem, x, W1t, dinv, bufA, N, (int)blockIdx.x - nblkc);
        return;
    }
    int* cur = (int*)smem;        // NBMAX ints
    int* ts2 = cur + NBMAX;       // 256 ints
    // scan buckettotal (nb ints, L2-hot); cursors = bucketbase + colbase[c0]
    int c0 = (int)blockIdx.x * (CHC / CHH);
    int v4[4];
    int tsum = 0;
#pragma unroll
    for (int k = 0; k < 4; ++k) {
        int bb = t * 4 + k;
        v4[k] = (bb < nb) ? buckettotal[bb] : 0;
        tsum += v4[k];
    }
    ts2[t] = tsum;
    __syncthreads();
    for (int ofs = 1; ofs < 256; ofs <<= 1) {
        int val = (t >= ofs) ? ts2[t - ofs] : 0;
        __syncthreads();
        ts2[t] += val;
        __syncthreads();
    }
    int run = ts2[t] - tsum;
#pragma unroll
    for (int k = 0; k < 4; ++k) {
        int bb = t * 4 + k;
        if (bb < nb) cur[bb] = run + colbase[(size_t)c0 * nb + bb];
        run += v4[k];
    }
    __syncthreads();
    int base = (int)blockIdx.x * CHC;
#pragma unroll 4
    for (int j = 0; j < CHC / 1024; ++j) {
        int idx = base + j * 1024 + t * 4;
        if (idx + 4 <= E) {
            int4 d = *(const int4*)(dst + idx);
            int4 s = *(const int4*)(src + idx);
            int p;
            p = atomicAdd(&cur[d.x >> BSHIFT], 1); packed[p] = ((d.x & 127) << 17) | s.x;
            p = atomicAdd(&cur[d.y >> BSHIFT], 1); packed[p] = ((d.y & 127) << 17) | s.y;
            p = atomicAdd(&cur[d.z >> BSHIFT], 1); packed[p] = ((d.z & 127) << 17) | s.z;
            p = atomicAdd(&cur[d.w >> BSHIFT], 1); packed[p] = ((d.w & 127) << 17) | s.w;
        } else if (idx < E) {
            for (int k = 0; k < 4; ++k)
                if (idx + k < E) {
                    int dd = dst[idx + k], ss = src[idx + k];
                    int p = atomicAdd(&cur[dd >> BSHIFT], 1);
                    packed[p] = ((dd & 127) << 17) | ss;
                }
        }
    }
}

// ---- pass D: within-bucket CSR + rowptr (deg from global) -----------------
__global__ __launch_bounds__(256) void bcsr_kernel(const int* __restrict__ packed,
                                                   const int* __restrict__ buckettotal,
                                                   const int* __restrict__ deg_g,
                                                   int* __restrict__ rowptr,
                                                   int* __restrict__ csr,
                                                   int N, int nb) {
    __shared__ int deg[128];
    __shared__ int lrp[128];
    __shared__ int ts[128];
    __shared__ int ts2[256];
    __shared__ int shbb[2];
    __shared__ int ebuf[MAXB];
    __shared__ int obuf[MAXB];
    int b = blockIdx.x;
    int t = threadIdx.x;
    int node0 = b << BSHIFT;
    if (t < 128) {
        int node = node0 + t;
        deg[t] = (node < N) ? deg_g[node] : 0;
    }
    // in-block scan of buckettotal -> [bb0, bb1)
    int v4[4];
    int tsum = 0;
#pragma unroll
    for (int k = 0; k < 4; ++k) {
        int bb = t * 4 + k;
        v4[k] = (bb < nb) ? buckettotal[bb] : 0;
        tsum += v4[k];
    }
    ts2[t] = tsum;
    __syncthreads();
    for (int ofs = 1; ofs < 256; ofs <<= 1) {
        int val = (t >= ofs) ? ts2[t - ofs] : 0;
        __syncthreads();
        ts2[t] += val;
        __syncthreads();
    }
    int run = ts2[t] - tsum;
#pragma unroll
    for (int k = 0; k < 4; ++k) {
        int bb = t * 4 + k;
        if (bb == b) { shbb[0] = run; shbb[1] = run + v4[k]; }
        run += v4[k];
    }
    __syncthreads();
    int bb0 = shbb[0];
    int bb1 = shbb[1];
    int cnt = bb1 - bb0;
    bool fits = (cnt <= MAXB);
    if (fits) {
        for (int i = t; i < cnt; i += 256) ebuf[i] = packed[bb0 + i];
    }
    if (t < 128) ts[t] = deg[t];
    __syncthreads();
    for (int ofs = 1; ofs < 128; ofs <<= 1) {
        int v = (t < 128 && t >= ofs) ? ts[t - ofs] : 0;
        __syncthreads();
        if (t < 128) ts[t] += v;
        __syncthreads();
    }
    int nlocal = min(128, N - node0);
    if (t < 128) lrp[t] = ts[t] - deg[t];
    if (t < nlocal) rowptr[node0 + t] = bb0 + (ts[t] - deg[t]);
    if (t == nlocal) rowptr[node0 + nlocal] = bb1;
    __syncthreads();
    if (fits) {
        for (int i = t; i < cnt; i += 256) {
            int v = ebuf[i];
            int p = atomicAdd(&lrp[v >> 17], 1);
            obuf[p] = v & 0x1FFFF;
        }
        __syncthreads();
        for (int i = t; i < cnt; i += 256) csr[bb0 + i] = obuf[i];  // coalesced
    } else {
        for (int i = t; i < cnt; i += 256) {
            int v = packed[bb0 + i];
            int p = atomicAdd(&lrp[v >> 17], 1);
            csr[bb0 + p] = v & 0x1FFFF;
        }
    }
}

// ---------------- aggregation kernels ----------------
#define ACC8(v)                                      \
    acc[0] += blo(v.x); acc[1] += bhi(v.x);          \
    acc[2] += blo(v.y); acc[3] += bhi(v.y);          \
    acc[4] += blo(v.z); acc[5] += bhi(v.z);          \
    acc[6] += blo(v.w); acc[7] += bhi(v.w);

#define GATHER_BODY                                                     \
    {                                                                   \
        uint4 v = *(const uint4*)(hsu + (size_t)node * 32 + sub * 4);   \
        acc[0] = blo(v.x); acc[1] = bhi(v.x);                           \
        acc[2] = blo(v.y); acc[3] = bhi(v.y);                           \
        acc[4] = blo(v.z); acc[5] = bhi(v.z);                           \
        acc[6] = blo(v.w); acc[7] = bhi(v.w);                           \
    }                                                                   \
    int e0 = rowptr[node];                                              \
    int e1 = rowptr[node + 1];                                          \
    int e = e0;                                                         \
    for (; e + 8 <= e1; e += 8) {                                       \
        int idx = csr[e + sub];                                         \
        int s0 = __shfl(idx, gbase + 0, 64);                            \
        int s1 = __shfl(idx, gbase + 1, 64);                            \
        int s2 = __shfl(idx, gbase + 2, 64);                            \
        int s3 = __shfl(idx, gbase + 3, 64);                            \
        int s4 = __shfl(idx, gbase + 4, 64);                            \
        int s5 = __shfl(idx, gbase + 5, 64);                            \
        int s6 = __shfl(idx, gbase + 6, 64);                            \
        int s7 = __shfl(idx, gbase + 7, 64);                            \
        uint4 v0 = *(const uint4*)(hsu + (size_t)s0 * 32 + sub * 4);    \
        uint4 v1 = *(const uint4*)(hsu + (size_t)s1 * 32 + sub * 4);    \
        uint4 v2 = *(const uint4*)(hsu + (size_t)s2 * 32 + sub * 4);    \
        uint4 v3 = *(const uint4*)(hsu + (size_t)s3 * 32 + sub * 4);    \
        uint4 v4 = *(const uint4*)(hsu + (size_t)s4 * 32 + sub * 4);    \
        uint4 v5 = *(const uint4*)(hsu + (size_t)s5 * 32 + sub * 4);    \
        uint4 v6 = *(const uint4*)(hsu + (size_t)s6 * 32 + sub * 4);    \
        uint4 v7 = *(const uint4*)(hsu + (size_t)s7 * 32 + sub * 4);    \
        ACC8(v0); ACC8(v1); ACC8(v2); ACC8(v3);                         \
        ACC8(v4); ACC8(v5); ACC8(v6); ACC8(v7);                         \
    }                                                                   \
    for (; e < e1; ++e) {                                               \
        int s = csr[e];                                                 \
        uint4 v = *(const uint4*)(hsu + (size_t)s * 32 + sub * 4);      \
        ACC8(v);                                                        \
    }

// layer 1: gather -> relu(agg*dinv+b1) -> per-wave MFMA (@W2) -> *dinv -> bufB
__global__ __launch_bounds__(256) void aggregate_gemm_kernel(
        const unsigned* __restrict__ hsu, const int* __restrict__ rowptr,
        const int* __restrict__ csr, const float* __restrict__ dinv,
        const float* __restrict__ bias, const unsigned short* __restrict__ W2t,
        unsigned short* __restrict__ outb, int N) {
    __shared__ unsigned short W2s[64 * 72];   // 9216 B
    __shared__ unsigned short Cs[4][8 * 72];  // 4608 B, wave-private patches
    int t = threadIdx.x;
    // stage W2 (one barrier, BEFORE the divergent-length gather)
    for (int i = t; i < 64 * 64 / 8; i += 256) {
        int r = i >> 3, c8 = i & 7;
        *(uint4*)(&W2s[r * 72 + c8 * 8]) = ((const uint4*)W2t)[i];
    }
    __syncthreads();

    int node0 = blockIdx.x * 32;
    int node = node0 + (t >> 3);
    int sub = t & 7;
    int gbase = t & 56;

    float acc[8] = {0.f, 0.f, 0.f, 0.f, 0.f, 0.f, 0.f, 0.f};
    uint4 pk = make_uint4(0u, 0u, 0u, 0u);
    if (node < N) {
        GATHER_BODY
        float d = dinv[node];
        float4 b0 = *(const float4*)(bias + sub * 8);
        float4 b1 = *(const float4*)(bias + sub * 8 + 4);
        float o0 = fmaxf(fmaf(acc[0], d, b0.x), 0.f);
        float o1 = fmaxf(fmaf(acc[1], d, b0.y), 0.f);
        float o2 = fmaxf(fmaf(acc[2], d, b0.z), 0.f);
        float o3 = fmaxf(fmaf(acc[3], d, b0.w), 0.f);
        float o4 = fmaxf(fmaf(acc[4], d, b1.x), 0.f);
        float o5 = fmaxf(fmaf(acc[5], d, b1.y), 0.f);
        float o6 = fmaxf(fmaf(acc[6], d, b1.z), 0.f);
        float o7 = fmaxf(fmaf(acc[7], d, b1.w), 0.f);
        pk.x = pack2(o0, o1); pk.y = pack2(o2, o3);
        pk.z = pack2(o4, o5); pk.w = pack2(o6, o7);
    }

    // per-wave MFMA: A[16][64], rows 0-7 = this wave's 8 nodes (rows 8-15 = 0).
    // ALL shfls issued with full exec (convergent); select AFTER. Sources
    // sl0/sl1 span lanes outside the am-subset, so divergent shfl = UB (the
    // R11/R12 bug).
    int lane = t & 63;
    int m16 = lane & 15;
    int q = lane >> 4;
    int wv = t >> 6;
    int wnode0 = node0 + wv * 8;
    bool am = (m16 < 8);
    int sl0 = ((m16 & 7) << 3) + q;       // src lane for s=0 frag
    int sl1 = sl0 + 4;                    // src lane for s=1 frag
    unsigned a00 = (unsigned)__shfl((int)pk.x, sl0, 64);
    unsigned a01 = (unsigned)__shfl((int)pk.y, sl0, 64);
    unsigned a02 = (unsigned)__shfl((int)pk.z, sl0, 64);
    unsigned a03 = (unsigned)__shfl((int)pk.w, sl0, 64);
    unsigned a10 = (unsigned)__shfl((int)pk.x, sl1, 64);
    unsigned a11 = (unsigned)__shfl((int)pk.y, sl1, 64);
    unsigned a12 = (unsigned)__shfl((int)pk.z, sl1, 64);
    unsigned a13 = (unsigned)__shfl((int)pk.w, sl1, 64);
    U8 fa0, fa1;
    fa0.u[0] = am ? a00 : 0u;
    fa0.u[1] = am ? a01 : 0u;
    fa0.u[2] = am ? a02 : 0u;
    fa0.u[3] = am ? a03 : 0u;
    fa1.u[0] = am ? a10 : 0u;
    fa1.u[1] = am ? a11 : 0u;
    fa1.u[2] = am ? a12 : 0u;
    fa1.u[3] = am ? a13 : 0u;

    unsigned short* Cw = &Cs[wv][0];
#pragma unroll
    for (int nt = 0; nt < 4; ++nt) {
        bf16x8 bb0 = *(const bf16x8*)(&W2s[(nt * 16 + m16) * 72 + q * 8]);
        bf16x8 bb1 = *(const bf16x8*)(&W2s[(nt * 16 + m16) * 72 + 32 + q * 8]);
        f32x4 c4 = (f32x4){0.f, 0.f, 0.f, 0.f};
        c4 = __builtin_amdgcn_mfma_f32_16x16x32_bf16(fa0.v, bb0, c4, 0, 0, 0);
        c4 = __builtin_amdgcn_mfma_f32_16x16x32_bf16(fa1.v, bb1, c4, 0, 0, 0);
        if (q < 2) {
#pragma unroll
            for (int r = 0; r < 4; ++r) {
                int row = q * 4 + r;       // 0..7 -> this wave's node row
                int gn = wnode0 + row;
                float dd = (gn < N) ? dinv[gn] : 0.f;
                Cw[row * 72 + nt * 16 + m16] = f2bf(c4[r] * dd);
            }
        }
    }
    // wave-private LDS readback (no cross-wave hazard -> no barrier needed)
    int row = lane >> 3, c8 = lane & 7;
    int gn = wnode0 + row;
    if (gn < N)
        *(uint4*)(outb + (size_t)gn * 64 + c8 * 8) = *(const uint4*)(&Cw[row * 72 + c8 * 8]);
}

// layer 2: gather -> agg*dinv + b2 -> fp32 out
__global__ __launch_bounds__(256) void aggregate_out_kernel(
        const unsigned* __restrict__ hsu, const int* __restrict__ rowptr,
        const int* __restrict__ csr, const float* __restrict__ dinv,
        const float* __restrict__ bias, float* __restrict__ outv, int N) {
    int t = threadIdx.x;
    int node = blockIdx.x * 32 + (t >> 3);
    if (node >= N) return;
    int sub = t & 7;
    int gbase = t & 56;
    float acc[8];
    GATHER_BODY
    float d = dinv[node];
    float4 b0 = *(const float4*)(bias + sub * 8);
    float4 b1 = *(const float4*)(bias + sub * 8 + 4);
    float o[8];
    o[0] = fmaf(acc[0], d, b0.x); o[1] = fmaf(acc[1], d, b0.y);
    o[2] = fmaf(acc[2], d, b0.z); o[3] = fmaf(acc[3], d, b0.w);
    o[4] = fmaf(acc[4], d, b1.x); o[5] = fmaf(acc[5], d, b1.y);
    o[6] = fmaf(acc[6], d, b1.z); o[7] = fmaf(acc[7], d, b1.w);
    float* op = outv + (size_t)node * 64 + sub * 8;
    *(float4*)(op)     = make_float4(o[0], o[1], o[2], o[3]);
    *(float4*)(op + 4) = make_float4(o[4], o[5], o[6], o[7]);
}

// ---------------- launch ----------------
extern "C" void kernel_launch(void* const* d_in, const int* in_sizes, int n_in,
                              void* d_out, int out_size, void* d_ws, size_t ws_size,
                              hipStream_t stream) {
    const float* x  = (const float*)d_in[0];
    const int*   ei = (const int*)d_in[1];   // [2, E] int32
    const float* W1 = (const float*)d_in[2];
    const float* b1 = (const float*)d_in[3];
    const float* W2 = (const float*)d_in[4];
    const float* b2 = (const float*)d_in[5];

    const int N = in_sizes[0] / 128;  // 100000
    const int E = in_sizes[1] / 2;    // 3200000
    const int* src = ei;
    const int* dst = ei + E;
    float* out = (float*)d_out;

    const int nb    = (N + 127) >> BSHIFT;   // 782
    const int nblkh = (E + CHH - 1) / CHH;   // 391
    const int nblkc = (E + CHC - 1) / CHC;   // 98
    const int ngemm1 = (N + 63) / 64;        // 1563

    char* ws = (char*)d_ws;
    size_t off = 0;
    auto alloc = [&](size_t bytes) -> char* {
        char* p = ws + off;
        off = (off + bytes + 255) & ~(size_t)255;
        return p;
    };
    // persistent
    int*   csr         = (int*)alloc((size_t)E * 4);
    int*   rowptr      = (int*)alloc((size_t)(N + 1) * 4);
    float* dinv        = (float*)alloc((size_t)N * 4);
    int*   deg_g       = (int*)alloc((size_t)N * 4);
    int*   buckettotal = (int*)alloc((size_t)nb * 4);
    unsigned short* W1t = (unsigned short*)alloc(64 * 128 * 2);
    unsigned short* W2t = (unsigned short*)alloc(64 * 64 * 2);
    unsigned short* bufA = (unsigned short*)alloc((size_t)N * 64 * 2);  // bf16 (xW1)*dinv
    unsigned short* bufB = (unsigned short*)alloc((size_t)N * 64 * 2);  // bf16 (hW2)*dinv
    // aliases:
    //  - histmat (nblkh*nb*4 ~ 1.22 MB) lives in the csr region: its last
    //    read (bscatter) strictly precedes bcsr's csr writes.
    //  - packed aliases bufB: consumed by bcsr BEFORE agg1 writes bufB.
    int* histmat = csr;
    int* packed  = (int*)bufB;  // E*4 = 12.8 MB == N*64*2

    hipMemsetAsync(deg_g, 0, (size_t)N * 4, stream);
    hist_kernel<<<nblkh + 48, 256, 0, stream>>>(dst, histmat, E, nb, nblkh,
                                                W1, W2, W1t, W2t, deg_g);
    scancol_kernel<<<nb, 256, 0, stream>>>(histmat, histmat, buckettotal, nb, nblkh,
                                           deg_g, dinv, N);
    bscatter_gemm1_kernel<<<nblkc + ngemm1, 256, 0, stream>>>(
        src, dst, histmat, buckettotal, packed, E, nb, nblkc, x, W1t, dinv, bufA, N);
    bcsr_kernel<<<nb, 256, 0, stream>>>(packed, buckettotal, deg_g, rowptr, csr, N, nb);

    aggregate_gemm_kernel<<<(N + 31) / 32, 256, 0, stream>>>(
        (const unsigned*)bufA, rowptr, csr, dinv, b1, W2t, bufB, N);
    aggregate_out_kernel<<<(N + 31) / 32, 256, 0, stream>>>(
        (const unsigned*)bufB, rowptr, csr, dinv, b2, out, N);
}

// Round 8
// 315.100 us; speedup vs baseline: 1.4105x; 1.4105x over previous
//
#include <hip/hip_runtime.h>
#include <cstdint>

// ===================== GCN encoder on MI355X =====================
// out = gcn(relu(gcn(x, W1, b1)), W2, b2)
// gcn(x,W,b)[i] = dinv[i] * ( sum_{e: dst=i} (xW*dinv)[src] + (xW*dinv)[i] ) + b
// dinv = rsqrt(indeg+1) (self-loop), identical for both layers.
//
// R14 = R10 structure (310us) + R13's now-correct per-wave agg1 epilogue.
// R13 lesson: per-edge global atomics for deg_g cost ~110us in hist
// (3.2M device-scope RMWs -> 101MB write-through, occupancy 14%) — far
// more than the ~12us the gemm1 co-dispatch saved. Reverted: deg/dinv
// computed in bcsr from packed (LDS atomics), gemm1 standalone.
// agg1: W2 staged once (barrier BEFORE gather), then per-wave shfl-built
// A-fragments -> 8 MFMA -> wave-private C patch -> store. No post-gather
// barrier (R10's +11us = block barrier coupling 32 degree tails).
// Shfls issued with full exec mask (R11/R12's divergent-shfl UB fixed).

#define BSHIFT 7          // 128 nodes per bucket
#define NBMAX 784         // >= ceil(100000/128) = 782
#define CH 8192           // edges per block in passes A/C
#define MAXB 6016         // LDS-cached bucket capacity (avg 4092, +30 sigma)

typedef __attribute__((ext_vector_type(8))) short bf16x8;
typedef __attribute__((ext_vector_type(4))) float f32x4;

union U8 { unsigned u[4]; bf16x8 v; };

// ---------------- bf16 helpers ----------------
__device__ inline unsigned short f2bf(float f) {
    unsigned u = __float_as_uint(f);
    unsigned r = (u + 0x7FFFu + ((u >> 16) & 1u)) >> 16;  // RNE
    return (unsigned short)r;
}
__device__ inline unsigned pack2(float a, float b) {
    return (unsigned)f2bf(a) | ((unsigned)f2bf(b) << 16);
}
__device__ inline float blo(unsigned u) { return __uint_as_float(u << 16); }
__device__ inline float bhi(unsigned u) { return __uint_as_float(u & 0xFFFF0000u); }

// ---------------- pass A: bucket histogram (+ folded weight prep) ----------
__global__ __launch_bounds__(256) void hist_kernel(const int* __restrict__ dst,
                                                   int* __restrict__ histmat,
                                                   int E, int nb, int nblk,
                                                   const float* __restrict__ W1,
                                                   const float* __restrict__ W2,
                                                   unsigned short* __restrict__ W1t,
                                                   unsigned short* __restrict__ W2t) {
    if (blockIdx.x >= (unsigned)nblk) {
        // weight-prep blocks: W[K][64] fp32 -> Wt[64][K] bf16
        int i = (blockIdx.x - nblk) * 256 + threadIdx.x;
        if (i < 128 * 64) {
            int k = i >> 6, n = i & 63;
            W1t[n * 128 + k] = f2bf(W1[i]);
        }
        int j = i - 128 * 64;
        if (j >= 0 && j < 64 * 64) {
            int k = j >> 6, n = j & 63;
            W2t[n * 64 + k] = f2bf(W2[j]);
        }
        return;
    }
    __shared__ int hist[NBMAX];
    int t = threadIdx.x;
    for (int b = t; b < nb; b += 256) hist[b] = 0;
    __syncthreads();
    int base = blockIdx.x * CH;
#pragma unroll
    for (int j = 0; j < CH / 1024; ++j) {
        int idx = base + j * 1024 + t * 4;
        if (idx + 4 <= E) {
            int4 d = *(const int4*)(dst + idx);
            atomicAdd(&hist[d.x >> BSHIFT], 1);
            atomicAdd(&hist[d.y >> BSHIFT], 1);
            atomicAdd(&hist[d.z >> BSHIFT], 1);
            atomicAdd(&hist[d.w >> BSHIFT], 1);
        } else {
            for (int k = 0; k < 4; ++k)
                if (idx + k < E) atomicAdd(&hist[dst[idx + k] >> BSHIFT], 1);
        }
    }
    __syncthreads();
    for (int b = t; b < nb; b += 256) histmat[blockIdx.x * nb + b] = hist[b];
}

// ---------------- pass B: per-bucket scan over blocks (nblk <= 1024) --------
__global__ __launch_bounds__(256) void scancol_kernel(const int* __restrict__ histmat,
                                                      int* __restrict__ colbase,
                                                      int* __restrict__ buckettotal,
                                                      int nb, int nblk) {
    __shared__ int ts[256];
    int b = blockIdx.x;
    int t = threadIdx.x;
    int v[4];
    int tsum = 0;
#pragma unroll
    for (int k = 0; k < 4; ++k) {
        int blk = t * 4 + k;
        v[k] = (blk < nblk) ? histmat[blk * nb + b] : 0;
        tsum += v[k];
    }
    ts[t] = tsum;
    __syncthreads();
    for (int ofs = 1; ofs < 256; ofs <<= 1) {
        int val = (t >= ofs) ? ts[t - ofs] : 0;
        __syncthreads();
        ts[t] += val;
        __syncthreads();
    }
    int run = ts[t] - tsum;
#pragma unroll
    for (int k = 0; k < 4; ++k) {
        int blk = t * 4 + k;
        if (blk < nblk) colbase[blk * nb + b] = run;
        run += v[k];
    }
    if (t == 255) buckettotal[b] = ts[255];
}

// ---------------- pass C: scatter into bucket regions (LDS cursors) ---------
// bucketbase computed in-block from buckettotal (no scanbucket dispatch).
__global__ __launch_bounds__(256) void bscatter_kernel(const int* __restrict__ src,
                                                       const int* __restrict__ dst,
                                                       const int* __restrict__ colbase,
                                                       const int* __restrict__ buckettotal,
                                                       int* __restrict__ packed,
                                                       int E, int nb) {
    __shared__ int cur[NBMAX];
    __shared__ int ts2[256];
    int t = threadIdx.x;
    int v4[4];
    int tsum = 0;
#pragma unroll
    for (int k = 0; k < 4; ++k) {
        int bb = t * 4 + k;
        v4[k] = (bb < nb) ? buckettotal[bb] : 0;
        tsum += v4[k];
    }
    ts2[t] = tsum;
    __syncthreads();
    for (int ofs = 1; ofs < 256; ofs <<= 1) {
        int val = (t >= ofs) ? ts2[t - ofs] : 0;
        __syncthreads();
        ts2[t] += val;
        __syncthreads();
    }
    int run = ts2[t] - tsum;
#pragma unroll
    for (int k = 0; k < 4; ++k) {
        int bb = t * 4 + k;
        if (bb < nb) cur[bb] = run + colbase[blockIdx.x * nb + bb];
        run += v4[k];
    }
    __syncthreads();
    int base = blockIdx.x * CH;
#pragma unroll
    for (int j = 0; j < CH / 1024; ++j) {
        int idx = base + j * 1024 + t * 4;
        if (idx + 4 <= E) {
            int4 d = *(const int4*)(dst + idx);
            int4 s = *(const int4*)(src + idx);
            int p;
            p = atomicAdd(&cur[d.x >> BSHIFT], 1); packed[p] = ((d.x & 127) << 17) | s.x;
            p = atomicAdd(&cur[d.y >> BSHIFT], 1); packed[p] = ((d.y & 127) << 17) | s.y;
            p = atomicAdd(&cur[d.z >> BSHIFT], 1); packed[p] = ((d.z & 127) << 17) | s.z;
            p = atomicAdd(&cur[d.w >> BSHIFT], 1); packed[p] = ((d.w & 127) << 17) | s.w;
        } else {
            for (int k = 0; k < 4; ++k)
                if (idx + k < E) {
                    int dd = dst[idx + k], ss = src[idx + k];
                    int p = atomicAdd(&cur[dd >> BSHIFT], 1);
                    packed[p] = ((dd & 127) << 17) | ss;
                }
        }
    }
}

// ---------------- pass D: within-bucket CSR + rowptr + dinv (LDS-cached) ----
__global__ __launch_bounds__(256) void bcsr_kernel(const int* __restrict__ packed,
                                                   const int* __restrict__ buckettotal,
                                                   int* __restrict__ rowptr,
                                                   float* __restrict__ dinv,
                                                   int* __restrict__ csr,
                                                   int N, int nb) {
    __shared__ int deg[128];
    __shared__ int lrp[128];
    __shared__ int ts[128];
    __shared__ int ts2[256];
    __shared__ int shbb[2];
    __shared__ int ebuf[MAXB];
    __shared__ int obuf[MAXB];
    int b = blockIdx.x;
    int t = threadIdx.x;
    if (t < 128) deg[t] = 0;
    // in-block scan of buckettotal -> [bb0, bb1)
    int v4[4];
    int tsum = 0;
#pragma unroll
    for (int k = 0; k < 4; ++k) {
        int bb = t * 4 + k;
        v4[k] = (bb < nb) ? buckettotal[bb] : 0;
        tsum += v4[k];
    }
    ts2[t] = tsum;
    __syncthreads();
    for (int ofs = 1; ofs < 256; ofs <<= 1) {
        int val = (t >= ofs) ? ts2[t - ofs] : 0;
        __syncthreads();
        ts2[t] += val;
        __syncthreads();
    }
    int run = ts2[t] - tsum;
#pragma unroll
    for (int k = 0; k < 4; ++k) {
        int bb = t * 4 + k;
        if (bb == b) { shbb[0] = run; shbb[1] = run + v4[k]; }
        run += v4[k];
    }
    __syncthreads();
    int bb0 = shbb[0];
    int bb1 = shbb[1];
    int cnt = bb1 - bb0;
    bool fits = (cnt <= MAXB);
    if (fits) {
        for (int i = t; i < cnt; i += 256) {
            int v = packed[bb0 + i];
            ebuf[i] = v;
            atomicAdd(&deg[v >> 17], 1);
        }
    } else {
        for (int i = t; i < cnt; i += 256)
            atomicAdd(&deg[packed[bb0 + i] >> 17], 1);
    }
    __syncthreads();
    if (t < 128) ts[t] = deg[t];
    __syncthreads();
    for (int ofs = 1; ofs < 128; ofs <<= 1) {
        int v = (t < 128 && t >= ofs) ? ts[t - ofs] : 0;
        __syncthreads();
        if (t < 128) ts[t] += v;
        __syncthreads();
    }
    int node0 = b << BSHIFT;
    int nlocal = min(128, N - node0);
    if (t < 128) lrp[t] = ts[t] - deg[t];
    if (t < nlocal) {
        rowptr[node0 + t] = bb0 + (ts[t] - deg[t]);
        dinv[node0 + t] = rsqrtf((float)(deg[t] + 1));
    }
    if (t == nlocal) rowptr[node0 + nlocal] = bb1;
    __syncthreads();
    if (fits) {
        for (int i = t; i < cnt; i += 256) {
            int v = ebuf[i];
            int p = atomicAdd(&lrp[v >> 17], 1);
            obuf[p] = v & 0x1FFFF;
        }
        __syncthreads();
        for (int i = t; i < cnt; i += 256) csr[bb0 + i] = obuf[i];  // coalesced
    } else {
        for (int i = t; i < cnt; i += 256) {
            int v = packed[bb0 + i];
            int p = atomicAdd(&lrp[v >> 17], 1);
            csr[bb0 + p] = v & 0x1FFFF;
        }
    }
}

// ------- MFMA GEMM1: bufA[M,64]bf16 = (X[M,128]f32 @ W1[128,64]) * dinv ----
__global__ __launch_bounds__(256) void gemm1_kernel(const float* __restrict__ X,
                                                    const unsigned short* __restrict__ Wt,
                                                    const float* __restrict__ dinv,
                                                    unsigned short* __restrict__ Ybf, int M) {
    constexpr int K = 128, KP = 136;
    __shared__ unsigned short Xs[64 * KP];   // reused as Cs (64*72) in epilogue
    __shared__ unsigned short Ws[64 * KP];
    int t = threadIdx.x;
    int row0 = blockIdx.x * 64;

    for (int i = t; i < 64 * K / 8; i += 256) {
        int r = i / (K / 8), c8 = i % (K / 8);
        *(uint4*)(&Ws[r * KP + c8 * 8]) = ((const uint4*)Wt)[i];
    }
    for (int i = t; i < 64 * K / 4; i += 256) {
        int r = i / (K / 4), c4 = i % (K / 4);
        int gr = row0 + r;
        float4 v = make_float4(0.f, 0.f, 0.f, 0.f);
        if (gr < M) v = ((const float4*)(X + (size_t)gr * K))[c4];
        uint2 p;
        p.x = pack2(v.x, v.y);
        p.y = pack2(v.z, v.w);
        *(uint2*)(&Xs[r * KP + c4 * 4]) = p;
    }
    __syncthreads();

    int lane = t & 63;
    int w = t >> 6;
    int m = lane & 15;
    int q = lane >> 4;

    f32x4 acc[4];
#pragma unroll
    for (int nt = 0; nt < 4; ++nt) acc[nt] = (f32x4){0.f, 0.f, 0.f, 0.f};

#pragma unroll
    for (int s = 0; s < K / 32; ++s) {
        bf16x8 a = *(const bf16x8*)(&Xs[(16 * w + m) * KP + s * 32 + q * 8]);
#pragma unroll
        for (int nt = 0; nt < 4; ++nt) {
            bf16x8 b = *(const bf16x8*)(&Ws[(16 * nt + m) * KP + s * 32 + q * 8]);
            acc[nt] = __builtin_amdgcn_mfma_f32_16x16x32_bf16(a, b, acc[nt], 0, 0, 0);
        }
    }
    __syncthreads();

    unsigned short* Cs = Xs;
#pragma unroll
    for (int nt = 0; nt < 4; ++nt)
#pragma unroll
        for (int r = 0; r < 4; ++r) {
            int row = 16 * w + q * 4 + r;
            int gr = row0 + row;
            float d = (gr < M) ? dinv[gr] : 0.f;
            Cs[row * 72 + nt * 16 + m] = f2bf(acc[nt][r] * d);
        }
    __syncthreads();
    for (int i = t; i < 64 * 64 / 8; i += 256) {
        int r = i >> 3, c8 = i & 7;
        int gr = row0 + r;
        if (gr < M)
            *(uint4*)(Ybf + (size_t)gr * 64 + c8 * 8) = *(const uint4*)(&Cs[r * 72 + c8 * 8]);
    }
}

// ---------------- aggregation kernels ----------------
#define ACC8(v)                                      \
    acc[0] += blo(v.x); acc[1] += bhi(v.x);          \
    acc[2] += blo(v.y); acc[3] += bhi(v.y);          \
    acc[4] += blo(v.z); acc[5] += bhi(v.z);          \
    acc[6] += blo(v.w); acc[7] += bhi(v.w);

#define GATHER_BODY                                                     \
    {                                                                   \
        uint4 v = *(const uint4*)(hsu + (size_t)node * 32 + sub * 4);   \
        acc[0] = blo(v.x); acc[1] = bhi(v.x);                           \
        acc[2] = blo(v.y); acc[3] = bhi(v.y);                           \
        acc[4] = blo(v.z); acc[5] = bhi(v.z);                           \
        acc[6] = blo(v.w); acc[7] = bhi(v.w);                           \
    }                                                                   \
    int e0 = rowptr[node];                                              \
    int e1 = rowptr[node + 1];                                          \
    int e = e0;                                                         \
    for (; e + 8 <= e1; e += 8) {                                       \
        int idx = csr[e + sub];                                         \
        int s0 = __shfl(idx, gbase + 0, 64);                            \
        int s1 = __shfl(idx, gbase + 1, 64);                            \
        int s2 = __shfl(idx, gbase + 2, 64);                            \
        int s3 = __shfl(idx, gbase + 3, 64);                            \
        int s4 = __shfl(idx, gbase + 4, 64);                            \
        int s5 = __shfl(idx, gbase + 5, 64);                            \
        int s6 = __shfl(idx, gbase + 6, 64);                            \
        int s7 = __shfl(idx, gbase + 7, 64);                            \
        uint4 v0 = *(const uint4*)(hsu + (size_t)s0 * 32 + sub * 4);    \
        uint4 v1 = *(const uint4*)(hsu + (size_t)s1 * 32 + sub * 4);    \
        uint4 v2 = *(const uint4*)(hsu + (size_t)s2 * 32 + sub * 4);    \
        uint4 v3 = *(const uint4*)(hsu + (size_t)s3 * 32 + sub * 4);    \
        uint4 v4 = *(const uint4*)(hsu + (size_t)s4 * 32 + sub * 4);    \
        uint4 v5 = *(const uint4*)(hsu + (size_t)s5 * 32 + sub * 4);    \
        uint4 v6 = *(const uint4*)(hsu + (size_t)s6 * 32 + sub * 4);    \
        uint4 v7 = *(const uint4*)(hsu + (size_t)s7 * 32 + sub * 4);    \
        ACC8(v0); ACC8(v1); ACC8(v2); ACC8(v3);                         \
        ACC8(v4); ACC8(v5); ACC8(v6); ACC8(v7);                         \
    }                                                                   \
    for (; e < e1; ++e) {                                               \
        int s = csr[e];                                                 \
        uint4 v = *(const uint4*)(hsu + (size_t)s * 32 + sub * 4);      \
        ACC8(v);                                                        \
    }

// layer 1: gather -> relu(agg*dinv+b1) -> per-wave MFMA (@W2) -> *dinv -> bufB
__global__ __launch_bounds__(256) void aggregate_gemm_kernel(
        const unsigned* __restrict__ hsu, const int* __restrict__ rowptr,
        const int* __restrict__ csr, const float* __restrict__ dinv,
        const float* __restrict__ bias, const unsigned short* __restrict__ W2t,
        unsigned short* __restrict__ outb, int N) {
    __shared__ unsigned short W2s[64 * 72];   // 9216 B
    __shared__ unsigned short Cs[4][8 * 72];  // 4608 B, wave-private patches
    int t = threadIdx.x;
    // stage W2 (single barrier, BEFORE the divergent-length gather)
    for (int i = t; i < 64 * 64 / 8; i += 256) {
        int r = i >> 3, c8 = i & 7;
        *(uint4*)(&W2s[r * 72 + c8 * 8]) = ((const uint4*)W2t)[i];
    }
    __syncthreads();

    int node0 = blockIdx.x * 32;
    int node = node0 + (t >> 3);
    int sub = t & 7;
    int gbase = t & 56;

    float acc[8] = {0.f, 0.f, 0.f, 0.f, 0.f, 0.f, 0.f, 0.f};
    uint4 pk = make_uint4(0u, 0u, 0u, 0u);
    if (node < N) {
        GATHER_BODY
        float d = dinv[node];
        float4 b0 = *(const float4*)(bias + sub * 8);
        float4 b1 = *(const float4*)(bias + sub * 8 + 4);
        float o0 = fmaxf(fmaf(acc[0], d, b0.x), 0.f);
        float o1 = fmaxf(fmaf(acc[1], d, b0.y), 0.f);
        float o2 = fmaxf(fmaf(acc[2], d, b0.z), 0.f);
        float o3 = fmaxf(fmaf(acc[3], d, b0.w), 0.f);
        float o4 = fmaxf(fmaf(acc[4], d, b1.x), 0.f);
        float o5 = fmaxf(fmaf(acc[5], d, b1.y), 0.f);
        float o6 = fmaxf(fmaf(acc[6], d, b1.z), 0.f);
        float o7 = fmaxf(fmaf(acc[7], d, b1.w), 0.f);
        pk.x = pack2(o0, o1); pk.y = pack2(o2, o3);
        pk.z = pack2(o4, o5); pk.w = pack2(o6, o7);
    }

    // per-wave MFMA: A[16][64], rows 0-7 = this wave's 8 nodes (rows 8-15 = 0).
    // Shfls with FULL exec (convergent); select after (divergent shfl = UB).
    int lane = t & 63;
    int m16 = lane & 15;
    int q = lane >> 4;
    int wv = t >> 6;
    int wnode0 = node0 + wv * 8;
    bool am = (m16 < 8);
    int sl0 = ((m16 & 7) << 3) + q;       // src lane for s=0 frag
    int sl1 = sl0 + 4;                    // src lane for s=1 frag
    unsigned a00 = (unsigned)__shfl((int)pk.x, sl0, 64);
    unsigned a01 = (unsigned)__shfl((int)pk.y, sl0, 64);
    unsigned a02 = (unsigned)__shfl((int)pk.z, sl0, 64);
    unsigned a03 = (unsigned)__shfl((int)pk.w, sl0, 64);
    unsigned a10 = (unsigned)__shfl((int)pk.x, sl1, 64);
    unsigned a11 = (unsigned)__shfl((int)pk.y, sl1, 64);
    unsigned a12 = (unsigned)__shfl((int)pk.z, sl1, 64);
    unsigned a13 = (unsigned)__shfl((int)pk.w, sl1, 64);
    U8 fa0, fa1;
    fa0.u[0] = am ? a00 : 0u;
    fa0.u[1] = am ? a01 : 0u;
    fa0.u[2] = am ? a02 : 0u;
    fa0.u[3] = am ? a03 : 0u;
    fa1.u[0] = am ? a10 : 0u;
    fa1.u[1] = am ? a11 : 0u;
    fa1.u[2] = am ? a12 : 0u;
    fa1.u[3] = am ? a13 : 0u;

    unsigned short* Cw = &Cs[wv][0];
#pragma unroll
    for (int nt = 0; nt < 4; ++nt) {
        bf16x8 bb0 = *(const bf16x8*)(&W2s[(nt * 16 + m16) * 72 + q * 8]);
        bf16x8 bb1 = *(const bf16x8*)(&W2s[(nt * 16 + m16) * 72 + 32 + q * 8]);
        f32x4 c4 = (f32x4){0.f, 0.f, 0.f, 0.f};
        c4 = __builtin_amdgcn_mfma_f32_16x16x32_bf16(fa0.v, bb0, c4, 0, 0, 0);
        c4 = __builtin_amdgcn_mfma_f32_16x16x32_bf16(fa1.v, bb1, c4, 0, 0, 0);
        if (q < 2) {
#pragma unroll
            for (int r = 0; r < 4; ++r) {
                int row = q * 4 + r;       // 0..7 -> this wave's node row
                int gn = wnode0 + row;
                float dd = (gn < N) ? dinv[gn] : 0.f;
                Cw[row * 72 + nt * 16 + m16] = f2bf(c4[r] * dd);
            }
        }
    }
    // wave-private LDS readback (no cross-wave hazard -> no barrier needed)
    int row = lane >> 3, c8 = lane & 7;
    int gn = wnode0 + row;
    if (gn < N)
        *(uint4*)(outb + (size_t)gn * 64 + c8 * 8) = *(const uint4*)(&Cw[row * 72 + c8 * 8]);
}

// layer 2: gather -> agg*dinv + b2 -> fp32 out
__global__ __launch_bounds__(256) void aggregate_out_kernel(
        const unsigned* __restrict__ hsu, const int* __restrict__ rowptr,
        const int* __restrict__ csr, const float* __restrict__ dinv,
        const float* __restrict__ bias, float* __restrict__ outv, int N) {
    int t = threadIdx.x;
    int node = blockIdx.x * 32 + (t >> 3);
    if (node >= N) return;
    int sub = t & 7;
    int gbase = t & 56;
    float acc[8];
    GATHER_BODY
    float d = dinv[node];
    float4 b0 = *(const float4*)(bias + sub * 8);
    float4 b1 = *(const float4*)(bias + sub * 8 + 4);
    float o[8];
    o[0] = fmaf(acc[0], d, b0.x); o[1] = fmaf(acc[1], d, b0.y);
    o[2] = fmaf(acc[2], d, b0.z); o[3] = fmaf(acc[3], d, b0.w);
    o[4] = fmaf(acc[4], d, b1.x); o[5] = fmaf(acc[5], d, b1.y);
    o[6] = fmaf(acc[6], d, b1.z); o[7] = fmaf(acc[7], d, b1.w);
    float* op = outv + (size_t)node * 64 + sub * 8;
    *(float4*)(op)     = make_float4(o[0], o[1], o[2], o[3]);
    *(float4*)(op + 4) = make_float4(o[4], o[5], o[6], o[7]);
}

// ---------------- launch ----------------
extern "C" void kernel_launch(void* const* d_in, const int* in_sizes, int n_in,
                              void* d_out, int out_size, void* d_ws, size_t ws_size,
                              hipStream_t stream) {
    const float* x  = (const float*)d_in[0];
    const int*   ei = (const int*)d_in[1];   // [2, E] int32
    const float* W1 = (const float*)d_in[2];
    const float* b1 = (const float*)d_in[3];
    const float* W2 = (const float*)d_in[4];
    const float* b2 = (const float*)d_in[5];

    const int N = in_sizes[0] / 128;  // 100000
    const int E = in_sizes[1] / 2;    // 3200000
    const int* src = ei;
    const int* dst = ei + E;
    float* out = (float*)d_out;

    const int nb   = (N + 127) >> BSHIFT;  // 782
    const int nblk = (E + CH - 1) / CH;    // 391

    char* ws = (char*)d_ws;
    size_t off = 0;
    auto alloc = [&](size_t bytes) -> char* {
        char* p = ws + off;
        off = (off + bytes + 255) & ~(size_t)255;
        return p;
    };
    // persistent
    int*   csr         = (int*)alloc((size_t)E * 4);
    int*   rowptr      = (int*)alloc((size_t)(N + 1) * 4);
    float* dinv        = (float*)alloc((size_t)N * 4);
    int*   buckettotal = (int*)alloc((size_t)nb * 4);
    unsigned short* W1t = (unsigned short*)alloc(64 * 128 * 2);
    unsigned short* W2t = (unsigned short*)alloc(64 * 64 * 2);
    unsigned short* bufA = (unsigned short*)alloc((size_t)N * 64 * 2);  // bf16 (xW1)*dinv
    unsigned short* bufB = (unsigned short*)alloc((size_t)N * 64 * 2);  // bf16 (hW2)*dinv
    // aliases:
    //  - histmat (nblk*nb*4 ~ 1.22 MB) in csr region: last read (bscatter)
    //    strictly precedes bcsr's csr writes.
    //  - packed aliases bufB: consumed by bcsr BEFORE agg1 writes bufB;
    //    gemm1 (writes bufA) runs after bcsr, no overlap with packed.
    int* histmat = csr;
    int* packed  = (int*)bufB;  // E*4 = 12.8 MB == N*64*2

    hist_kernel<<<nblk + 48, 256, 0, stream>>>(dst, histmat, E, nb, nblk, W1, W2, W1t, W2t);
    scancol_kernel<<<nb, 256, 0, stream>>>(histmat, histmat, buckettotal, nb, nblk);
    bscatter_kernel<<<nblk, 256, 0, stream>>>(src, dst, histmat, buckettotal, packed, E, nb);
    bcsr_kernel<<<nb, 256, 0, stream>>>(packed, buckettotal, rowptr, dinv, csr, N, nb);

    gemm1_kernel<<<(N + 63) / 64, 256, 0, stream>>>(x, W1t, dinv, bufA, N);
    aggregate_gemm_kernel<<<(N + 31) / 32, 256, 0, stream>>>(
        (const unsigned*)bufA, rowptr, csr, dinv, b1, W2t, bufB, N);
    aggregate_out_kernel<<<(N + 31) / 32, 256, 0, stream>>>(
        (const unsigned*)bufB, rowptr, csr, dinv, b2, out, N);
}